// Round 3
// baseline (199.496 us; speedup 1.0000x reference)
//
#include <hip/hip_runtime.h>
#include <stdint.h>

// VectorQuantizer on MI355X (gfx950), fp32 exact path, round 3.
// Key change: pass1 holds acc[64] (one 64-code chunk) in registers -- the
// compiler CANNOT rematerialize accumulators, unlike round 1/2 where it
// re-loaded x[] every iteration (VGPR=36, 2.1x VALU inflation). x is streamed
// one element per 64 FMAs from a TRANSPOSED copy xT[d][n] (coalesced b32
// loads); w is read in its natural [D][K] layout via wave-uniform s_loads.
// xT is staged in d_out's quantized region (exactly 16 MB) and overwritten by
// pass2 afterwards -- no workspace-size assumptions beyond round 2's ~1.2 MB.

#define N_PTS 65536
#define DDIM 64
#define KCODES 512
#define NCHUNK 8
#define KCHUNK 64  // KCODES / NCHUNK

// ws layout:
//   wT    : 512*64 f = 131072 B @ 0        (for pass2 row gather)
//   wsq   : 512 f    = 2048 B   @ 131072
//   xsq   : 65536 f  = 262144 B @ 133120
//   lossp : 4096 f   = 16384 B  @ 395264
//   minkey: 65536 u64= 524288 B @ 657408
// total ~1.18 MB (same footprint as round 2, which fit).

__global__ void vq_prep(const float* __restrict__ x_in,
                        const float* __restrict__ w,
                        float* __restrict__ xT,   // [64][65536], in d_out
                        float* __restrict__ wT, float* __restrict__ wsq,
                        unsigned long long* __restrict__ minkey) {
  __shared__ float tile[64][65];
  const int b = blockIdx.x;
  const int t = threadIdx.x;
  if (b < 1024) {
    // transpose a 64-point x tile: x[n0+r][d] -> xT[d][n0+r]
    const float4* src = (const float4*)(x_in + (size_t)b * 4096);
#pragma unroll
    for (int p = 0; p < 4; ++p) {
      int e = p * 1024 + t * 4;
      float4 v = src[p * 256 + t];          // coalesced 16B
      int r = e >> 6, c = e & 63;
      tile[r][c] = v.x; tile[r][c + 1] = v.y;
      tile[r][c + 2] = v.z; tile[r][c + 3] = v.w;
    }
    __syncthreads();
#pragma unroll
    for (int p = 0; p < 4; ++p) {
      int e = p * 1024 + t * 4;
      int d = e >> 6, c = e & 63;
      float4 v = make_float4(tile[c][d], tile[c + 1][d],
                             tile[c + 2][d], tile[c + 3][d]);
      *(float4*)(xT + (size_t)d * N_PTS + (size_t)b * 64 + c) = v;  // coalesced
    }
  } else {
    int g = (b - 1024) * 256 + t;  // 0..32767 over D*K
    int d = g >> 9, k = g & 511;
    wT[k * DDIM + d] = w[g];
    minkey[2 * g] = ~0ull;
    minkey[2 * g + 1] = ~0ull;
    if (g < KCODES) {
      float s = 0.f;
      for (int dd = 0; dd < DDIM; ++dd) {
        float tv = w[dd * KCODES + g];
        s = fmaf(tv, tv, s);
      }
      wsq[g] = s;
    }
  }
}

__global__ __launch_bounds__(256, 4)
void vq_pass1(const float* __restrict__ xT, const float* __restrict__ w,
              const float* __restrict__ wsq,
              unsigned long long* __restrict__ minkey,
              float* __restrict__ xsq_out) {
  const int chunk = blockIdx.x >> 8;                       // 0..7, uniform
  const int n = ((blockIdx.x & 255) << 8) | threadIdx.x;   // point id
  const int k0 = chunk << 6;

  float acc[KCHUNK];
#pragma unroll
  for (int c = 0; c < KCHUNK; ++c) acc[c] = 0.f;
  float sx = 0.f;

  const float* xp = xT + n;          // lane-varying, coalesced per d
  const float* wp = w + k0;          // wave-uniform -> s_load

#pragma unroll 4
  for (int d = 0; d < DDIM; ++d) {
    float xv = xp[(size_t)d << 16];  // xT[d][n]
    if (chunk == 0) sx = fmaf(xv, xv, sx);   // uniform branch per block
#pragma unroll
    for (int c = 0; c < KCHUNK; ++c) {
      acc[c] = fmaf(wp[d * KCODES + c], xv, acc[c]);  // sgpr * vgpr fmac
    }
  }

  if (chunk == 0) xsq_out[n] = sx;

  float best = 3.0e38f;
  int bidx = 0;
#pragma unroll
  for (int c = 0; c < KCHUNK; ++c) {
    float dist = fmaf(acc[c], -2.0f, wsq[k0 + c]);
    if (dist < best) { best = dist; bidx = k0 + c; }  // strict <: first-min
  }

  // sortable-float pack, idx in low bits -> exact ties pick lowest index
  unsigned int ub = __float_as_uint(best);
  ub = (ub & 0x80000000u) ? ~ub : (ub | 0x80000000u);
  unsigned long long key =
      ((unsigned long long)ub << 32) | (unsigned long long)(unsigned int)bidx;
  atomicMin(&minkey[n], key);
}

__global__ void vq_pass2(const float* __restrict__ wT,
                         const unsigned long long* __restrict__ minkey,
                         const float* __restrict__ xsq,
                         float4* __restrict__ out_q,
                         float* __restrict__ out_idx,
                         float* __restrict__ lossp) {
  __shared__ float red[64];
  const int g4 = blockIdx.x * 256 + threadIdx.x;  // over N*D/4
  const int n = g4 >> 4;
  const int d4 = g4 & 15;
  unsigned long long key = minkey[n];
  unsigned int idx = (unsigned int)(key & 0xFFFFFFFFull);
  out_q[g4] = ((const float4*)(wT + (size_t)idx * DDIM))[d4];
  if (d4 == 0) {
    out_idx[n] = (float)idx;
    unsigned int ub = (unsigned int)(key >> 32);
    unsigned int fb = (ub & 0x80000000u) ? (ub & 0x7FFFFFFFu) : ~ub;
    float dist = __uint_as_float(fb);          // ||q||^2 - 2 x.q
    red[threadIdx.x >> 4] = (dist + xsq[n]) * (1.25f / 4194304.0f);
  }
  __syncthreads();
  if (threadIdx.x == 0) {
    float s = 0.f;
#pragma unroll
    for (int i = 0; i < 16; ++i) s += red[i];
    lossp[blockIdx.x] = s;
  }
}

__global__ void vq_pass3(const float* __restrict__ lossp,
                         float* __restrict__ loss_out) {
  __shared__ float sm[256];
  const int t = threadIdx.x;
  float s = 0.f;
#pragma unroll
  for (int i = 0; i < 16; ++i) s += lossp[i * 256 + t];
  sm[t] = s;
  __syncthreads();
  for (int off = 128; off > 0; off >>= 1) {
    if (t < off) sm[t] += sm[t + off];
    __syncthreads();
  }
  if (t == 0) *loss_out = sm[0];
}

extern "C" void kernel_launch(void* const* d_in, const int* in_sizes, int n_in,
                              void* d_out, int out_size, void* d_ws, size_t ws_size,
                              hipStream_t stream) {
  const float* x = (const float*)d_in[0];  // (64,32,32,64) fp32
  const float* w = (const float*)d_in[1];  // (64,512) fp32

  char* ws = (char*)d_ws;
  float* wT = (float*)(ws);
  float* wsq = (float*)(ws + 131072);
  float* xsq = (float*)(ws + 133120);
  float* lossp = (float*)(ws + 395264);
  unsigned long long* minkey = (unsigned long long*)(ws + 657408);

  float* out_q = (float*)d_out;               // 4194304 floats
  float* out_idx = out_q + 4194304;           // 65536 floats (indices)
  float* loss_out = out_q + 4259840;          // 1 float
  float* xT = out_q;                          // reuse quantized region as xT
                                              // (16,777,216 B, exact fit;
                                              //  pass2 overwrites it after
                                              //  pass1 has consumed it)

  vq_prep<<<1152, 256, 0, stream>>>(x, w, xT, wT, wsq, minkey);
  vq_pass1<<<256 * NCHUNK, 256, 0, stream>>>(xT, w, wsq, minkey, xsq);
  vq_pass2<<<4096, 256, 0, stream>>>(wT, minkey, xsq, (float4*)out_q,
                                     out_idx, lossp);
  vq_pass3<<<1, 256, 0, stream>>>(lossp, loss_out);
}

// Round 4
// 134.346 us; speedup vs baseline: 1.4849x; 1.4849x over previous
//
#include <hip/hip_runtime.h>
#include <stdint.h>

// VectorQuantizer on MI355X (gfx950), fp32 exact path, round 4.
// Round-3 failure: acc[64] + unroll-4 + vector w-loads => acc spilled to
// scratch (VGPR=60, WRITE_SIZE 4352KB, VALUBusy 27%). Fix: 2pt x 16code tile
// (32 acc), d blocked by 8 with float2 x-prefetch; block-uniform code set so
// w addresses are wave-uniform (round-1-style s_load promotion, SGPR=112
// there); x streamed coalesced from transposed xT.

#define N_PTS 65536
#define DDIM 64
#define KCODES 512

// ws layout:
//   wT    : 512*64 f = 131072 B @ 0        (pass2 row gather)
//   wsq   : 512 f    = 2048 B   @ 131072
//   xsq   : 65536 f  = 262144 B @ 133120
//   lossp : 4096 f   = 16384 B  @ 395264
//   minkey: 65536 u64= 524288 B @ 657408

__global__ void vq_prep(const float* __restrict__ x_in,
                        const float* __restrict__ w,
                        float* __restrict__ xT,   // [64][65536], in d_out
                        float* __restrict__ wT, float* __restrict__ wsq,
                        unsigned long long* __restrict__ minkey) {
  __shared__ float tile[64][65];
  const int b = blockIdx.x;
  const int t = threadIdx.x;
  if (b < 1024) {
    // transpose a 64-point x tile: x[n0+r][d] -> xT[d][n0+r]
    const float4* src = (const float4*)(x_in + (size_t)b * 4096);
#pragma unroll
    for (int p = 0; p < 4; ++p) {
      int e = p * 1024 + t * 4;
      float4 v = src[p * 256 + t];          // coalesced 16B
      int r = e >> 6, c = e & 63;
      tile[r][c] = v.x; tile[r][c + 1] = v.y;
      tile[r][c + 2] = v.z; tile[r][c + 3] = v.w;
    }
    __syncthreads();
#pragma unroll
    for (int p = 0; p < 4; ++p) {
      int e = p * 1024 + t * 4;
      int d = e >> 6, c = e & 63;
      float4 v = make_float4(tile[c][d], tile[c + 1][d],
                             tile[c + 2][d], tile[c + 3][d]);
      *(float4*)(xT + (size_t)d * N_PTS + (size_t)b * 64 + c) = v;  // coalesced
    }
  } else {
    int g = (b - 1024) * 256 + t;  // 0..32767 over D*K
    int d = g >> 9, k = g & 511;
    wT[k * DDIM + d] = w[g];
    minkey[2 * g] = ~0ull;
    minkey[2 * g + 1] = ~0ull;
    if (g < KCODES) {
      float s = 0.f;
      for (int dd = 0; dd < DDIM; ++dd) {
        float tv = w[dd * KCODES + g];
        s = fmaf(tv, tv, s);
      }
      wsq[g] = s;
    }
  }
}

__global__ __launch_bounds__(256, 4)
void vq_pass1(const float* __restrict__ xT, const float* __restrict__ w,
              const float* __restrict__ wsq,
              unsigned long long* __restrict__ minkey,
              float* __restrict__ xsq_out) {
  const int kb = blockIdx.x & 31;        // code-block id, wave-uniform
  const int pb = blockIdx.x >> 5;        // point-block 0..127
  const int k0 = kb << 4;                // 16 codes for the WHOLE block
  const int n0 = (pb << 9) | (threadIdx.x << 1);  // 2 adjacent points

  float acc0[16], acc1[16];
#pragma unroll
  for (int c = 0; c < 16; ++c) { acc0[c] = 0.f; acc1[c] = 0.f; }
  float sx0 = 0.f, sx1 = 0.f;

  const float* xp = xT + n0;
  const float* wp = w + k0;              // uniform base -> s_load candidates

#pragma unroll 1
  for (int d8 = 0; d8 < 8; ++d8) {
    float2 xa[8];
#pragma unroll
    for (int dd = 0; dd < 8; ++dd)
      xa[dd] = *(const float2*)(xp + ((size_t)(d8 * 8 + dd) << 16));
    if (kb == 0) {  // uniform branch: only code-block 0 computes ||x||^2
#pragma unroll
      for (int dd = 0; dd < 8; ++dd) {
        sx0 = fmaf(xa[dd].x, xa[dd].x, sx0);
        sx1 = fmaf(xa[dd].y, xa[dd].y, sx1);
      }
    }
#pragma unroll
    for (int dd = 0; dd < 8; ++dd) {
      const float* wd = wp + (size_t)(d8 * 8 + dd) * KCODES;
#pragma unroll
      for (int c = 0; c < 16; ++c) {
        float wv = wd[c];                // 16 consecutive, wave-uniform
        acc0[c] = fmaf(wv, xa[dd].x, acc0[c]);
        acc1[c] = fmaf(wv, xa[dd].y, acc1[c]);
      }
    }
  }
  if (kb == 0) { xsq_out[n0] = sx0; xsq_out[n0 + 1] = sx1; }

  float best0 = 3.0e38f, best1 = 3.0e38f;
  int b0 = 0, b1 = 0;
#pragma unroll
  for (int c = 0; c < 16; ++c) {
    float wq = wsq[k0 + c];
    float d0 = fmaf(acc0[c], -2.0f, wq);
    float d1 = fmaf(acc1[c], -2.0f, wq);
    if (d0 < best0) { best0 = d0; b0 = k0 + c; }  // strict <: first-min wins
    if (d1 < best1) { best1 = d1; b1 = k0 + c; }
  }

  // sortable-float pack, idx in low bits -> exact ties pick lowest index
  unsigned int u0 = __float_as_uint(best0);
  u0 = (u0 & 0x80000000u) ? ~u0 : (u0 | 0x80000000u);
  unsigned int u1 = __float_as_uint(best1);
  u1 = (u1 & 0x80000000u) ? ~u1 : (u1 | 0x80000000u);
  atomicMin(&minkey[n0],
            ((unsigned long long)u0 << 32) | (unsigned int)b0);
  atomicMin(&minkey[n0 + 1],
            ((unsigned long long)u1 << 32) | (unsigned int)b1);
}

__global__ void vq_pass2(const float* __restrict__ wT,
                         const unsigned long long* __restrict__ minkey,
                         const float* __restrict__ xsq,
                         float4* __restrict__ out_q,
                         float* __restrict__ out_idx,
                         float* __restrict__ lossp) {
  __shared__ float red[64];
  const int g4 = blockIdx.x * 256 + threadIdx.x;  // over N*D/4
  const int n = g4 >> 4;
  const int d4 = g4 & 15;
  unsigned long long key = minkey[n];
  unsigned int idx = (unsigned int)(key & 0xFFFFFFFFull);
  out_q[g4] = ((const float4*)(wT + (size_t)idx * DDIM))[d4];
  if (d4 == 0) {
    out_idx[n] = (float)idx;
    unsigned int ub = (unsigned int)(key >> 32);
    unsigned int fb = (ub & 0x80000000u) ? (ub & 0x7FFFFFFFu) : ~ub;
    float dist = __uint_as_float(fb);          // ||q||^2 - 2 x.q
    red[threadIdx.x >> 4] = (dist + xsq[n]) * (1.25f / 4194304.0f);
  }
  __syncthreads();
  if (threadIdx.x == 0) {
    float s = 0.f;
#pragma unroll
    for (int i = 0; i < 16; ++i) s += red[i];
    lossp[blockIdx.x] = s;
  }
}

__global__ void vq_pass3(const float* __restrict__ lossp,
                         float* __restrict__ loss_out) {
  __shared__ float sm[256];
  const int t = threadIdx.x;
  float s = 0.f;
#pragma unroll
  for (int i = 0; i < 16; ++i) s += lossp[i * 256 + t];
  sm[t] = s;
  __syncthreads();
  for (int off = 128; off > 0; off >>= 1) {
    if (t < off) sm[t] += sm[t + off];
    __syncthreads();
  }
  if (t == 0) *loss_out = sm[0];
}

extern "C" void kernel_launch(void* const* d_in, const int* in_sizes, int n_in,
                              void* d_out, int out_size, void* d_ws, size_t ws_size,
                              hipStream_t stream) {
  const float* x = (const float*)d_in[0];  // (64,32,32,64) fp32
  const float* w = (const float*)d_in[1];  // (64,512) fp32

  char* ws = (char*)d_ws;
  float* wT = (float*)(ws);
  float* wsq = (float*)(ws + 131072);
  float* xsq = (float*)(ws + 133120);
  float* lossp = (float*)(ws + 395264);
  unsigned long long* minkey = (unsigned long long*)(ws + 657408);

  float* out_q = (float*)d_out;               // 4194304 floats
  float* out_idx = out_q + 4194304;           // 65536 floats (indices)
  float* loss_out = out_q + 4259840;          // 1 float
  float* xT = out_q;                          // xT staged in d_out region;
                                              // pass2 overwrites after use

  vq_prep<<<1152, 256, 0, stream>>>(x, w, xT, wT, wsq, minkey);
  vq_pass1<<<128 * 32, 256, 0, stream>>>(xT, w, wsq, minkey, xsq);
  vq_pass2<<<4096, 256, 0, stream>>>(wT, minkey, xsq, (float4*)out_q,
                                     out_idx, lossp);
  vq_pass3<<<1, 256, 0, stream>>>(lossp, loss_out);
}

// Round 5
// 130.742 us; speedup vs baseline: 1.5259x; 1.0276x over previous
//
#include <hip/hip_runtime.h>
#include <stdint.h>

// VectorQuantizer on MI355X (gfx950), fp32 exact path, round 5.
// Round-4 evidence: scalar w-loads worked (SGPR=112) but 32-way K-split
// re-fetched xT 32x (FETCH 64MB) and 2M cross-XCD atomicMin ping-ponged
// (WRITE 33MB) -> 36% idle. This round: one block = 64 points x ALL 512
// codes. x staged+transposed in LDS once (prep transpose deleted), 4
// threads/point each scan a 128-code quarter (readfirstlane keeps w
// addresses SGPR-rooted -> s_load), argmin completes in-LDS (global
// atomics deleted), epilogue writes quantized+idx+loss directly
// (pass2/pass3 deleted). 2 kernels total; x read from HBM exactly once.

#define N_PTS 65536
#define DDIM 64
#define KCODES 512

// ws: wT 131072 B @ 0, wsq 2048 B @ 131072  (~133 KB total)

__global__ void vq_prep(const float* __restrict__ w, float* __restrict__ wT,
                        float* __restrict__ wsq, float* __restrict__ loss_out) {
  int g = blockIdx.x * 256 + threadIdx.x;  // 128 blocks over D*K
  int d = g >> 9, k = g & 511;
  wT[k * DDIM + d] = w[g];                 // [K][D] copy for epilogue gather
  if (g < KCODES) {
    float s = 0.f;
    for (int dd = 0; dd < DDIM; ++dd) {
      float t = w[dd * KCODES + g];
      s = fmaf(t, t, s);
    }
    wsq[g] = s;
  }
  if (g == 0) *loss_out = 0.f;             // d_out is poisoned each launch
}

__global__ __launch_bounds__(256, 4)
void vq_main(const float* __restrict__ x_in, const float* __restrict__ w,
             const float* __restrict__ wT, const float* __restrict__ wsq,
             float* __restrict__ out_q, float* __restrict__ out_idx,
             float* __restrict__ loss_out) {
  __shared__ float xs[DDIM][65];                 // transposed x tile (+1 pad)
  __shared__ unsigned long long sm_key[4 * 64];  // per-quarter packed keys
  __shared__ unsigned int sm_idx[64];
  __shared__ float sm_loss[64];

  const int t = threadIdx.x;
  const int pb = blockIdx.x;  // 1024 blocks, 64 points each

  // ---- stage: coalesced read of 64 pts x 64 d, transpose into LDS ----
  {
    const float4* src = (const float4*)(x_in + (size_t)pb * 4096);
#pragma unroll
    for (int i = 0; i < 4; ++i) {
      float4 v = src[i * 256 + t];   // coalesced 16B/lane
      int e = (i * 256 + t) * 4;
      int pt = e >> 6, d = e & 63;
      xs[d][pt] = v.x; xs[d + 1][pt] = v.y;
      xs[d + 2][pt] = v.z; xs[d + 3][pt] = v.w;  // <=2-way bank alias: free
    }
  }
  __syncthreads();

  // quarter id: wave-uniform by construction; readfirstlane makes it an SGPR
  // so all w/wsq addresses stay scalar -> s_load promotion (round-4 proven).
  const int q = __builtin_amdgcn_readfirstlane(t >> 6);
  const int pt = t & 63;        // lane id = point id
  const int kq = q << 7;        // this wave's 128-code range

  float best = 3.0e38f;
  int bidx = 0;
  float sx = 0.f;

#pragma unroll 1
  for (int kb = 0; kb < 8; ++kb) {
    const int k0 = kq + (kb << 4);
    const float* wp = w + k0;   // scalar base
    float acc[16];
#pragma unroll
    for (int c = 0; c < 16; ++c) acc[c] = 0.f;
#pragma unroll 1
    for (int d8 = 0; d8 < 8; ++d8) {
      float xv[8];
#pragma unroll
      for (int dd = 0; dd < 8; ++dd) xv[dd] = xs[d8 * 8 + dd][pt];  // conflict-free
      if (q == 0 && kb == 0) {  // uniform branch; ||x||^2 once per point
#pragma unroll
        for (int dd = 0; dd < 8; ++dd) sx = fmaf(xv[dd], xv[dd], sx);
      }
#pragma unroll
      for (int dd = 0; dd < 8; ++dd) {
        const float* wd = wp + (size_t)(d8 * 8 + dd) * KCODES;
#pragma unroll
        for (int c = 0; c < 16; ++c)
          acc[c] = fmaf(wd[c], xv[dd], acc[c]);  // sgpr * vgpr fmac
      }
    }
#pragma unroll
    for (int c = 0; c < 16; ++c) {
      float dist = fmaf(acc[c], -2.0f, wsq[k0 + c]);
      if (dist < best) { best = dist; bidx = k0 + c; }  // strict <: first-min
    }
  }

  // sortable-float pack, idx in low bits -> exact ties pick lowest index
  unsigned int ub = __float_as_uint(best);
  ub = (ub & 0x80000000u) ? ~ub : (ub | 0x80000000u);
  sm_key[(q << 6) | pt] =
      ((unsigned long long)ub << 32) | (unsigned long long)(unsigned int)bidx;
  __syncthreads();

  // ---- merge quarters; write idx + loss partial (t<64 is q==0, owns sx) ----
  if (t < 64) {
    unsigned long long k = sm_key[t];
    unsigned long long k1 = sm_key[64 + t];
    unsigned long long k2 = sm_key[128 + t];
    unsigned long long k3 = sm_key[192 + t];
    k = k1 < k ? k1 : k;
    k = k2 < k ? k2 : k;
    k = k3 < k ? k3 : k;
    unsigned int idx = (unsigned int)k;
    sm_idx[t] = idx;
    out_idx[(size_t)pb * 64 + t] = (float)idx;
    unsigned int u = (unsigned int)(k >> 32);
    u = (u & 0x80000000u) ? (u & 0x7FFFFFFFu) : ~u;
    // ||x-q||^2 = sx + (||q||^2 - 2 x.q); pre-scale by 1.25/(N*D)
    sm_loss[t] = (__uint_as_float(u) + sx) * (1.25f / 4194304.0f);
  }
  __syncthreads();

  // ---- epilogue: gather code rows, coalesced write of 64x64 out tile ----
  float4* dst = (float4*)(out_q + (size_t)pb * 4096);
#pragma unroll
  for (int i = 0; i < 4; ++i) {
    int e = (i * 256 + t) * 4;
    int p2 = e >> 6, d = e & 63;
    unsigned int idx = sm_idx[p2];   // LDS broadcast (16 lanes share)
    float4 v = *(const float4*)(wT + (size_t)idx * DDIM + d);  // L2-hot gather
    dst[i * 256 + t] = v;            // coalesced 16B/lane
  }

  if (t == 0) {
    float s = 0.f;
#pragma unroll
    for (int i = 0; i < 64; ++i) s += sm_loss[i];
    atomicAdd(loss_out, s);          // 1024 adds total
  }
}

extern "C" void kernel_launch(void* const* d_in, const int* in_sizes, int n_in,
                              void* d_out, int out_size, void* d_ws, size_t ws_size,
                              hipStream_t stream) {
  const float* x = (const float*)d_in[0];  // (64,32,32,64) fp32
  const float* w = (const float*)d_in[1];  // (64,512) fp32

  char* ws = (char*)d_ws;
  float* wT = (float*)(ws);
  float* wsq = (float*)(ws + 131072);

  float* out_q = (float*)d_out;            // 4194304 floats
  float* out_idx = out_q + 4194304;        // 65536 floats (indices)
  float* loss_out = out_q + 4259840;       // 1 float

  vq_prep<<<128, 256, 0, stream>>>(w, wT, wsq, loss_out);
  vq_main<<<1024, 256, 0, stream>>>(x, w, wT, wsq, out_q, out_idx, loss_out);
}